// Round 12
// baseline (85.834 us; speedup 1.0000x reference)
//
#include <hip/hip_runtime.h>

#define B_ 16
#define N_ 16384
#define D_ 256
#define G_ 256
#define EPSF 1e-6f
#define CHUNKS 16
#define CROWS (N_/CHUNKS)   // 1024 rows per chunk

// ---- DPP wave-64 sum: row_shr 1/2/4/8 + row_bcast15/31, broadcast via readlane(63).
template <int CTRL>
__device__ __forceinline__ float dpp_add_step(float x) {
    const int y = __builtin_amdgcn_update_dpp(0, __float_as_int(x), CTRL, 0xF, 0xF, false);
    return x + __int_as_float(y);
}
__device__ __forceinline__ float wave_sum64(float x) {
    x = dpp_add_step<0x111>(x);   // row_shr:1
    x = dpp_add_step<0x112>(x);   // row_shr:2
    x = dpp_add_step<0x114>(x);   // row_shr:4
    x = dpp_add_step<0x118>(x);   // row_shr:8
    x = dpp_add_step<0x142>(x);   // row_bcast15
    x = dpp_add_step<0x143>(x);   // row_bcast31 -> lane 63 has wave total
    return __int_as_float(__builtin_amdgcn_readlane(__float_as_int(x), 63));
}

// ---- K0a: per-chunk histogram (256 blocks = 16 images x 16 chunks) ----
__global__ __launch_bounds__(256) void k_hist(const int* __restrict__ gt,
                                              int* __restrict__ chist,
                                              int* __restrict__ done) {
    __shared__ int h[G_];
    const int tid = threadIdx.x, blk = blockIdx.x;
    if (blk == 0 && tid == 0) done[0] = 0;
    h[tid] = 0;
    __syncthreads();
    const int4 g4 = *(const int4*)&gt[blk*CROWS + tid*4];
    atomicAdd(&h[g4.x], 1);
    atomicAdd(&h[g4.y], 1);
    atomicAdd(&h[g4.z], 1);
    atomicAdd(&h[g4.w], 1);
    __syncthreads();
    chist[blk*G_ + tid] = h[tid];
}

// ---- K0b: per-chunk scan + scatter (256 blocks) ----
__global__ __launch_bounds__(256) void k_scatscan(const int* __restrict__ gt,
                                                  const int* __restrict__ chist,
                                                  int* __restrict__ counts,
                                                  int* __restrict__ starts,
                                                  int* __restrict__ sorted) {
    __shared__ int scn[G_];
    __shared__ int cur[G_];
    const int g = threadIdx.x, blk = blockIdx.x;
    const int b = blk >> 4, chunk = blk & 15;

    int tot = 0, pre = 0;
    #pragma unroll
    for (int cc = 0; cc < CHUNKS; ++cc) {
        const int v = chist[((b<<4) + cc)*G_ + g];
        pre += (cc < chunk) ? v : 0;
        tot += v;
    }
    scn[g] = tot;
    __syncthreads();
    for (int off = 1; off < G_; off <<= 1) {
        const int v2 = (g >= off) ? scn[g - off] : 0;
        __syncthreads();
        scn[g] += v2;
        __syncthreads();
    }
    const int st = scn[g] - tot;               // exclusive over groups
    if (chunk == 0) { counts[b*G_ + g] = tot; starts[b*G_ + g] = st; }
    cur[g] = st + pre;
    __syncthreads();

    const int rbase = chunk * CROWS;
    const int4 g4 = *(const int4*)&gt[b*N_ + rbase + g*4];
    const int r = rbase + g*4;
    int* sb = sorted + b*N_;
    sb[atomicAdd(&cur[g4.x], 1)] = r;
    sb[atomicAdd(&cur[g4.y], 1)] = r + 1;
    sb[atomicAdd(&cur[g4.z], 1)] = r + 2;
    sb[atomicAdd(&cur[g4.w], 1)] = r + 3;
}

// ---- K1: ONE wave per (b,g) group; 16 rows in flight; weighted padding so
//      every batch is full (no serial tail). No LDS, no barriers, no atomics.
__global__ __launch_bounds__(256, 4) void k_fused(const float* __restrict__ pred,
                                                  const int* __restrict__ sorted,
                                                  const int* __restrict__ starts,
                                                  const int* __restrict__ counts,
                                                  float* __restrict__ sums,
                                                  float* __restrict__ pull_g) {
    const int tid = threadIdx.x, lane = tid & 63, w = tid >> 6;
    const int gi = (blockIdx.x << 2) | w;          // = b*G_ + g
    const int b = gi >> 8;
    const int start = starts[gi], cnt = counts[gi];
    const int c = lane * 4;

    if (cnt == 0) {
        float4 z = make_float4(0.f,0.f,0.f,0.f);
        *(float4*)&sums[(size_t)gi*D_ + c] = z;
        if (lane == 0) pull_g[gi] = 0.f;
        return;                                    // wave-level return
    }

    const float* predb = pred + (size_t)b*N_*D_;
    const int*   sortb = sorted + b*N_ + start;

    float4 acc  = make_float4(0.f,0.f,0.f,0.f);    // S (this lane's 4 dims)
    float4 uacc = make_float4(0.f,0.f,0.f,0.f);    // U

    if (cnt <= 128) {
        // lane-parallel row-id prefetch into 2 VGPRs
        const int ids0 = sortb[min(lane, cnt-1)];
        int ids1 = 0;
        if (cnt > 64) ids1 = sortb[min(64 + lane, cnt-1)];

        for (int i = 0; i < cnt; i += 16) {
            float4 p[16];
            float  wt[16];
            #pragma unroll
            for (int u = 0; u < 16; ++u) {
                const int k  = i + u;
                const int kk = min(k, cnt - 1);    // pad batches re-read last row
                const int r  = (kk < 64) ? __builtin_amdgcn_readlane(ids0, kk)
                                         : __builtin_amdgcn_readlane(ids1, kk - 64);
                p[u]  = *(const float4*)&predb[(size_t)r*D_ + c];
                wt[u] = (k < cnt) ? 1.f : 0.f;     // pad rows contribute x0 (exact)
            }
            #pragma unroll
            for (int u = 0; u < 16; ++u) {
                float n = p[u].x*p[u].x + p[u].y*p[u].y + p[u].z*p[u].z + p[u].w*p[u].w;
                n = wave_sum64(n);
                const float q = __frsqrt_rn(n) * wt[u];
                acc.x  += p[u].x * wt[u];  acc.y  += p[u].y * wt[u];
                acc.z  += p[u].z * wt[u];  acc.w  += p[u].w * wt[u];
                uacc.x += p[u].x * q;      uacc.y += p[u].y * q;
                uacc.z += p[u].z * q;      uacc.w += p[u].w * q;
            }
        }
    } else {
        // generic fallback (statistically never hit at Poisson(64))
        for (int i = 0; i < cnt; ++i) {
            const int r0 = sortb[i];
            const float4 p0 = *(const float4*)&predb[(size_t)r0*D_ + c];
            const float n0 = wave_sum64(p0.x*p0.x + p0.y*p0.y + p0.z*p0.z + p0.w*p0.w);
            const float q0 = __frsqrt_rn(n0);
            acc.x  += p0.x;    acc.y  += p0.y;    acc.z  += p0.z;    acc.w  += p0.w;
            uacc.x += p0.x*q0; uacc.y += p0.y*q0; uacc.z += p0.z*q0; uacc.w += p0.w*q0;
        }
    }

    *(float4*)&sums[(size_t)gi*D_ + c] = acc;
    const float ssq = wave_sum64(acc.x*acc.x + acc.y*acc.y + acc.z*acc.z + acc.w*acc.w);
    const float dus = wave_sum64(uacc.x*acc.x + uacc.y*acc.y + uacc.z*acc.z + uacc.w*acc.w);
    if (lane == 0) pull_g[gi] = (float)cnt - dus / sqrtf(ssq);
}

// ---- K2: per-image push + pull combine; last image-finisher writes out[0] ----
__global__ __launch_bounds__(256) void k_tags(const float* __restrict__ sums,
                                              const int* __restrict__ counts,
                                              const float* __restrict__ pull_g,
                                              float* __restrict__ lossv,
                                              int* __restrict__ done,
                                              float* __restrict__ out) {
    const int b = blockIdx.x;
    const int tid = threadIdx.x;
    const int lane = tid & 63;
    const int wave = tid >> 6;
    __shared__ float s_acc[D_];
    __shared__ float redA[256];
    __shared__ float redB[256];

    for (int i = tid; i < D_; i += 256) s_acc[i] = 0.f;
    __syncthreads();

    const int c = lane * 4;
    float4 sl = make_float4(0.f, 0.f, 0.f, 0.f);
    for (int g = wave; g < G_; g += 4) {
        const int cnt = counts[b*G_ + g];
        const float inv = 1.0f / fmaxf((float)cnt, 1.0f);
        const float4 sm = *(const float4*)&sums[((size_t)(b*G_ + g))*D_ + c];
        const float tx = sm.x*inv, tyv = sm.y*inv, tz = sm.z*inv, tw = sm.w*inv;
        const float sq = wave_sum64(tx*tx + tyv*tyv + tz*tz + tw*tw);
        if (cnt > 0) {
            const float it = __frsqrt_rn(sq);
            sl.x += tx*it; sl.y += tyv*it; sl.z += tz*it; sl.w += tw*it;
        }
    }
    atomicAdd(&s_acc[c+0], sl.x);
    atomicAdd(&s_acc[c+1], sl.y);
    atomicAdd(&s_acc[c+2], sl.z);
    atomicAdd(&s_acc[c+3], sl.w);
    __syncthreads();

    const int cnt_t = counts[b*G_ + tid];
    const float v = s_acc[tid];
    redA[tid] = v * v;
    redB[tid] = (cnt_t > 0) ? 1.f : 0.f;
    __syncthreads();
    for (int s = 128; s > 0; s >>= 1) {
        if (tid < s) { redA[tid] += redA[tid + s]; redB[tid] += redB[tid + s]; }
        __syncthreads();
    }
    float ssq = 0.f, obj = 0.f;
    if (tid == 0) { ssq = redA[0]; obj = redB[0]; }
    __syncthreads();

    redA[tid] = (cnt_t > 0) ? pull_g[b*G_ + tid] / (float)cnt_t : 0.f;
    __syncthreads();
    for (int s = 128; s > 0; s >>= 1) {
        if (tid < s) redA[tid] += redA[tid + s];
        __syncthreads();
    }
    if (tid == 0) {
        const float push = (obj*obj - 2.f*obj + ssq) / (((obj - 1.f)*obj + EPSF) * 2.f);
        const float pull = redA[0] / (obj + EPSF);
        const float loss = (obj > 1.f) ? (push + pull) : 0.f;
        __hip_atomic_store(&lossv[b], loss, __ATOMIC_RELEASE, __HIP_MEMORY_SCOPE_AGENT);
        const int o = __hip_atomic_fetch_add(&done[0], 1, __ATOMIC_ACQ_REL,
                                             __HIP_MEMORY_SCOPE_AGENT);
        if (o == B_ - 1) {    // last image: final mean
            float t = 0.f;
            #pragma unroll
            for (int bb = 0; bb < B_; ++bb)
                t += __hip_atomic_load(&lossv[bb], __ATOMIC_RELAXED, __HIP_MEMORY_SCOPE_AGENT);
            out[0] = t * (1.0f / (float)B_);
        }
    }
}

extern "C" void kernel_launch(void* const* d_in, const int* in_sizes, int n_in,
                              void* d_out, int out_size, void* d_ws, size_t ws_size,
                              hipStream_t stream) {
    const float* pred = (const float*)d_in[0];
    const int*   gt   = (const int*)d_in[1];
    float* out = (float*)d_out;

    char* ws = (char*)d_ws;
    const size_t SZ_SUMS = (size_t)B_*G_*D_*sizeof(float);   // 4 MiB
    const size_t SZ_I    = (size_t)B_*G_*sizeof(int);        // 16 KiB each

    float* sums    = (float*)ws;                               ws += SZ_SUMS;
    int*   counts  = (int*)ws;                                 ws += SZ_I;
    int*   starts  = (int*)ws;                                 ws += SZ_I;
    float* pull_g  = (float*)ws;                               ws += SZ_I;
    float* lossv   = (float*)ws;                               ws += 64*sizeof(float);
    int*   done    = (int*)ws;                                 ws += 64*sizeof(int);
    int*   sorted  = (int*)ws;                                 ws += (size_t)B_*N_*sizeof(int);  // 1 MiB
    int*   chist   = (int*)ws;                                 // B*CHUNKS*G ints = 256 KiB

    k_hist     <<<B_*CHUNKS, 256, 0, stream>>>(gt, chist, done);
    k_scatscan <<<B_*CHUNKS, 256, 0, stream>>>(gt, chist, counts, starts, sorted);
    k_fused    <<<B_*G_/4,   256, 0, stream>>>(pred, sorted, starts, counts, sums, pull_g);
    k_tags     <<<B_,        256, 0, stream>>>(sums, counts, pull_g, lossv, done, out);
}